// Round 4
// baseline (135.204 us; speedup 1.0000x reference)
//
#include <hip/hip_runtime.h>
#include <hip/hip_bf16.h>
#include <math.h>

#define BB 4
#define CC 192
#define HH 56
#define WW 56
#define HWW 3136

typedef __attribute__((ext_vector_type(8))) short short8;
typedef __attribute__((ext_vector_type(4))) float f32x4;

__device__ __forceinline__ unsigned short f2b(float f) {
    __hip_bfloat16 h = __float2bfloat16(f);
    return __builtin_bit_cast(unsigned short, h);
}
__device__ __forceinline__ float b2f(unsigned short u) {
    unsigned int x = ((unsigned int)u) << 16;
    return __builtin_bit_cast(float, x);
}

// ---------------------------------------------------------------------------
// Kernel 1: blocks [0,2352): transpose x (B,C,H,W) -> split-bf16 xth/xtl (B,HW,C)
//           blocks [2352,2640): W' = [C1;C2] -> split bf16 (N=384, K=192)
// hi/lo here are bit-identical to what the GEMM used to compute from f32 xt.
// ---------------------------------------------------------------------------
__global__ __launch_bounds__(256) void k_pre(const float* __restrict__ x,
                                             const float* __restrict__ cw,
                                             unsigned short* __restrict__ xth,
                                             unsigned short* __restrict__ xtl,
                                             unsigned short* __restrict__ cwh,
                                             unsigned short* __restrict__ cwl) {
    int tid = threadIdx.x, bid = blockIdx.x;
    if (bid < 2352) {
        __shared__ float tile[32][33];
        int b = bid / 588, rem = bid % 588;
        int by = rem / 98, bx = rem % 98;
        int tx = tid & 31, ty = tid >> 5;
        int p0 = bx * 32, c0 = by * 32;
#pragma unroll
        for (int i = 0; i < 4; i++) {
            int c = c0 + ty + 8 * i;
            tile[ty + 8 * i][tx] = x[(b * CC + c) * HWW + p0 + tx];
        }
        __syncthreads();
#pragma unroll
        for (int i = 0; i < 4; i++) {
            int p = p0 + ty + 8 * i;
            float v = tile[tx][ty + 8 * i];
            unsigned short hi = f2b(v);
            size_t o = (size_t)(b * HWW + p) * CC + c0 + tx;
            xth[o] = hi;
            xtl[o] = f2b(v - b2f(hi));
        }
    } else {
        int i = (bid - 2352) * 256 + tid;     // 288*256 = 73728 = 384*192 exact
        if (i < 384 * 192) {
            int n = i / 192, k = i % 192;
            float v = (n < 192) ? cw[n * 384 + k] : cw[(n - 192) * 384 + 192 + k];
            unsigned short hi = f2b(v);
            cwh[i] = hi;
            cwl[i] = f2b(v - b2f(hi));
        }
    }
}

// ---------------------------------------------------------------------------
// Kernel 2 (fused independent work, reads xth/xtl/cwh/cwl only):
//   blocks [0,1792):    scores (pair symmetry) -> sp [half][b][pix][32]
//   blocks [1792,2968): GEMM [u|z] = W'·x^T, M=12544, N=384, K=192, split-bf16.
//                       Staging is now pure short8 copies (no f2b in-loop).
// ---------------------------------------------------------------------------
__global__ __launch_bounds__(256) void k_mid(const unsigned short* __restrict__ xth,
                                             const unsigned short* __restrict__ xtl,
                                             const unsigned short* __restrict__ cwh,
                                             const unsigned short* __restrict__ cwl,
                                             float* __restrict__ sp,
                                             float* __restrict__ u,
                                             float* __restrict__ z) {
    __shared__ __align__(16) char smem[36864];
    int tid = threadIdx.x, bid = blockIdx.x;

    if (bid < 1792) {                 // ---------------- scores ----------------
        float* Xs = (float*)smem;     // 28 rows x 96ch (+4 pad), f32 reconstructed
        const float K2 = 0.38490017945975050f;  // 2/sqrt(27)
        bool isH = bid < 896;
        int lid = isH ? bid : bid - 896;
        int half = lid & 1;
        int rp = (lid >> 1) & 1;
        int cb2 = lid >> 2;
        int b = cb2 / 56, l0 = cb2 % 56;
        int r0 = rp * 2;

        const unsigned short* srch = xth + (size_t)(b * HWW) * CC + half * 96;
        const unsigned short* srcl = xtl + (size_t)(b * HWW) * CC + half * 96;
        for (int idx = tid; idx < 28 * 12; idx += 256) {
            int t2 = idx / 12, cq = idx % 12;
            int pi = (r0 + t2 / 14) + 4 * (t2 % 14);
            int pix = isH ? (pi * WW + l0) : (l0 * WW + pi);
            short8 h8 = *(const short8*)(srch + (size_t)pix * CC + cq * 8);
            short8 l8 = *(const short8*)(srcl + (size_t)pix * CC + cq * 8);
            float o[8];
#pragma unroll
            for (int e = 0; e < 8; e++)
                o[e] = b2f((unsigned short)h8[e]) + b2f((unsigned short)l8[e]);
            *(float4*)&Xs[t2 * 100 + cq * 8] = *(float4*)&o[0];
            *(float4*)&Xs[t2 * 100 + cq * 8 + 4] = *(float4*)&o[4];
        }
        __syncthreads();

        int perCls = isH ? 105 : 91;
        if (tid < 2 * perCls) {
            int cls = tid / perCls, p = tid % perCls;
            int a, bb;
            if (isH) {
                a = (int)((sqrtf((float)(8 * p + 1)) - 1.0f) * 0.5f);
                bb = p - (a * (a + 1)) / 2;
            } else {
                int ap = (int)((sqrtf((float)(8 * p + 1)) - 1.0f) * 0.5f);
                bb = p - (ap * (ap + 1)) / 2;
                a = ap + 1;
            }
            const float* pA = &Xs[(cls * 14 + a) * 100];
            const float* pB = &Xs[(cls * 14 + bb) * 100];
            float s0 = 0.f, s1 = 0.f, s2 = 0.f, s3 = 0.f;
#pragma unroll
            for (int q = 0; q < 24; q++) {
                float4 av = *(const float4*)(pA + q * 4);
                float4 bv = *(const float4*)(pB + q * 4);
                s0 += __builtin_amdgcn_rcpf(__expf(av.x * bv.x * K2) + 1.0f);
                s1 += __builtin_amdgcn_rcpf(__expf(av.y * bv.y * K2) + 1.0f);
                s2 += __builtin_amdgcn_rcpf(__expf(av.z * bv.z * K2) + 1.0f);
                s3 += __builtin_amdgcn_rcpf(__expf(av.w * bv.w * K2) + 1.0f);
            }
            float s = 96.0f - 2.0f * (s0 + s1 + s2 + s3);   // sum_c tanh
            int r = r0 + cls;
            size_t base = (size_t)(half * BB + b) * HWW;
            if (isH) {
                int i1 = a - bb;
                int h1 = r + 4 * a, h2 = r + 4 * bb;
                sp[(base + h1 * WW + l0) * 32 + i1] = s;
                if (a != bb) sp[(base + h2 * WW + l0) * 32 + (14 - i1)] = s;
            } else {
                int d = a - bb;                        // 1..13
                int w1 = r + 4 * a, w2 = r + 4 * bb;
                sp[(base + l0 * WW + w1) * 32 + 14 + (d - 1)] = s;
                sp[(base + l0 * WW + w2) * 32 + 14 + (13 - d)] = s;
            }
        }
        return;
    }

    // ---------------- GEMM [u|z], split-bf16, tile 64x64, K=192 ----------------
    {
        unsigned short* Ah = (unsigned short*)smem;
        unsigned short* Al = Ah + 64 * 72;
        unsigned short* Bh = Ah + 2 * 64 * 72;
        unsigned short* Bl = Ah + 3 * 64 * 72;
        float* Ds = (float*)smem;
        int vb = bid - 1792;                  // 0..1175
        int bm = (vb % 196) * 64, bn = (vb / 196) * 64;
        int lane = tid & 63, wv = tid >> 6;

        f32x4 acc[4] = {{0,0,0,0},{0,0,0,0},{0,0,0,0},{0,0,0,0}};

        for (int kc = 0; kc < 3; kc++) {
#pragma unroll
            for (int r2 = 0; r2 < 2; r2++) {
                int idx = tid + r2 * 256;
                int m = idx >> 3, kq = idx & 7;
                size_t ao = (size_t)(bm + m) * CC + kc * 64 + kq * 8;
                *(short8*)&Ah[m * 72 + kq * 8] = *(const short8*)(xth + ao);
                *(short8*)&Al[m * 72 + kq * 8] = *(const short8*)(xtl + ao);
                size_t bo = (size_t)(bn + m) * 192 + kc * 64 + kq * 8;
                *(short8*)&Bh[m * 72 + kq * 8] = *(const short8*)(cwh + bo);
                *(short8*)&Bl[m * 72 + kq * 8] = *(const short8*)(cwl + bo);
            }
            __syncthreads();
            int n0 = wv * 16;
            int k8 = lane >> 4;
            int col = lane & 15;
#pragma unroll
            for (int ks = 0; ks < 64; ks += 32) {
                int koff = ks + k8 * 8;
                short8 bfh = *(const short8*)&Bh[(n0 + col) * 72 + koff];
                short8 bfl = *(const short8*)&Bl[(n0 + col) * 72 + koff];
#pragma unroll
                for (int fm = 0; fm < 4; fm++) {
                    short8 afh = *(const short8*)&Ah[(fm * 16 + col) * 72 + koff];
                    short8 afl = *(const short8*)&Al[(fm * 16 + col) * 72 + koff];
                    acc[fm] = __builtin_amdgcn_mfma_f32_16x16x32_bf16(afh, bfh, acc[fm], 0, 0, 0);
                    acc[fm] = __builtin_amdgcn_mfma_f32_16x16x32_bf16(afl, bfh, acc[fm], 0, 0, 0);
                    acc[fm] = __builtin_amdgcn_mfma_f32_16x16x32_bf16(afh, bfl, acc[fm], 0, 0, 0);
                }
            }
            __syncthreads();
        }
        // LDS transpose: Ds[m][n], stride 68
        {
            int col = lane & 15, rowq = lane >> 4;
#pragma unroll
            for (int fm = 0; fm < 4; fm++)
#pragma unroll
                for (int rg = 0; rg < 4; rg++)
                    Ds[(fm * 16 + rowq * 4 + rg) * 68 + wv * 16 + col] = acc[fm][rg];
        }
        __syncthreads();
        // Store pixel-major: u (n<192) or z (n>=192)
        {
            int c4 = tid & 15, m0 = tid >> 4;
            int cg = bn + c4 * 4;
            float* dst = (cg < 192) ? u : z;
            int cc = (cg < 192) ? cg : cg - 192;
#pragma unroll
            for (int p = 0; p < 4; p++) {
                int m = m0 + p * 16;
                float4 v = *(float4*)&Ds[m * 68 + c4 * 4];
                *(float4*)&dst[(size_t)(bm + m) * CC + cc] = v;
            }
        }
    }
}

// ---------------------------------------------------------------------------
// Kernel 3: fused softmax + H+W accumulation + bias + BN + GELU.
// Block = (b, r-phase, 8-ch chunk, t-half): stages z rows ≡ r (mod 4) for its
// 8 channels into LDS (25 KB); softmax computed inline per (thread, pixel)
// from sp (c-lanes share cachelines); H-conv from registers, W-conv from LDS.
// Grid 768 = 4b x 4r x 24cc x 2th, 448 threads (tid = w*8+c).
// ---------------------------------------------------------------------------
__global__ __launch_bounds__(448) void k_tail(const float* __restrict__ u,
                                              const float* __restrict__ z,
                                              const float* __restrict__ sp,
                                              const float* __restrict__ cb,
                                              const float* __restrict__ gma,
                                              const float* __restrict__ bta,
                                              const float* __restrict__ mea,
                                              const float* __restrict__ var,
                                              float* __restrict__ y) {
    __shared__ float Zs[14 * 56 * 8];     // [t][w][c], c fastest -> conflict-free
    int tid = threadIdx.x, bid = blockIdx.x;
    int th = bid & 1;
    int t1 = bid >> 1;                    // 0..383
    int cc = t1 % 24;
    int t2 = t1 / 24;                     // 0..15
    int r = t2 & 3;
    int b = t2 >> 2;
    int w = tid >> 3, c = tid & 7;
    int cg = cc * 8 + c;

    // stage z slab: rows r, r+4, ..., r+52; all 56 w; channels [cc*8, cc*8+8)
#pragma unroll
    for (int it = 0; it < 2; it++) {
        int idx = tid + it * 448;
        if (idx < 784) {
            int t = idx / 56, ww = idx - t * 56;
            const float* s = z + ((size_t)(b * HWW + (r + 4 * t) * WW + ww)) * CC + cc * 8;
            float4 v0 = *(const float4*)s;
            float4 v1 = *(const float4*)(s + 4);
            float* d = &Zs[(t * 56 + ww) * 8];
            *(float4*)d = v0;
            *(float4*)(d + 4) = v1;
        }
    }
    __syncthreads();

    // this thread's z column, pre-rotated by th*7 so all reg indices are static
    float zc[14];
#pragma unroll
    for (int m = 0; m < 14; m++) {
        int t0 = m + th * 7;
        if (t0 >= 14) t0 -= 14;
        zc[m] = Zs[(t0 * 56 + w) * 8 + c];
    }

    float bias = cb[cg];
    float ginv = gma[cg] * rsqrtf(var[cg] + 1e-5f);
    float bt = bta[cg];
    float me = mea[cg];

    int hbase = r + 4 * (th * 7);
    float acc0[7];
#pragma unroll
    for (int tt = 0; tt < 7; tt++) {
        int pix = (hbase + 4 * tt) * WW + w;
        acc0[tt] = u[((size_t)(b * HWW + pix)) * CC + cg];
    }

#pragma unroll
    for (int tt = 0; tt < 7; tt++) {
        int t = th * 7 + tt;
        int pix = (hbase + 4 * tt) * WW + w;
        size_t gp = (size_t)b * HWW + pix;

        // inline softmax over the 27 scores of this pixel (sum of both halves)
        const float4* p0 = (const float4*)&sp[gp * 32];
        const float4* p1 = (const float4*)&sp[((size_t)(4 * HWW) + gp) * 32];
        float sc[28];
#pragma unroll
        for (int j = 0; j < 7; j++) {
            float4 a4 = p0[j], v4 = p1[j];
            sc[4 * j + 0] = a4.x + v4.x; sc[4 * j + 1] = a4.y + v4.y;
            sc[4 * j + 2] = a4.z + v4.z; sc[4 * j + 3] = a4.w + v4.w;
        }
        float mx = -1e30f;
#pragma unroll
        for (int s = 0; s < 27; s++) mx = fmaxf(mx, sc[s]);
        float sum = 0.f;
#pragma unroll
        for (int s = 0; s < 27; s++) { sc[s] = __expf(sc[s] - mx); sum += sc[s]; }
        float inv = __builtin_amdgcn_rcpf(sum);

        // weighted accumulation (inv folded out of the 27-term sum)
        float accw = 0.f;
#pragma unroll
        for (int i = 0; i < 14; i++)
            accw += sc[i] * zc[(tt - i + 14) % 14];
#pragma unroll
        for (int j = 1; j <= 13; j++) {
            int wj = w - 4 * j;
            if (wj < 0) wj += 56;
            accw += sc[13 + j] * Zs[(t * 56 + wj) * 8 + c];
        }
        float a = acc0[tt] + accw * inv;

        float v = (a + bias - me) * ginv + bt;
        v = 0.5f * v * (1.0f + erff(v * 0.70710678118654752f));
        y[((size_t)(b * CC + cg)) * HWW + pix] = v;
    }
}

// ---------------------------------------------------------------------------
extern "C" void kernel_launch(void* const* d_in, const int* in_sizes, int n_in,
                              void* d_out, int out_size, void* d_ws, size_t ws_size,
                              hipStream_t stream) {
    const float* x   = (const float*)d_in[0];
    const float* cw  = (const float*)d_in[1];
    const float* cb  = (const float*)d_in[2];
    const float* gma = (const float*)d_in[3];
    const float* bta = (const float*)d_in[4];
    const float* mea = (const float*)d_in[5];
    const float* var = (const float*)d_in[6];
    float* out = (float*)d_out;

    float* ws = (float*)d_ws;
    float*          sp  = ws;                                   //   802,816 f
    float*          u   = ws + 802816;                          // 2,408,448 f
    float*          z   = ws + 3211264;                         // 2,408,448 f
    unsigned short* xth = (unsigned short*)(ws + 5619712);      // 2,408,448 us
    unsigned short* xtl = (unsigned short*)(ws + 6823936);      // 2,408,448 us
    unsigned short* cwh = (unsigned short*)(ws + 8028160);      //    73,728 us
    unsigned short* cwl = (unsigned short*)(ws + 8065024);      //    73,728 us

    k_pre<<<2640, 256, 0, stream>>>(x, cw, xth, xtl, cwh, cwl);
    k_mid<<<2968, 256, 0, stream>>>(xth, xtl, cwh, cwl, sp, u, z);
    k_tail<<<768, 448, 0, stream>>>(u, z, sp, cb, gma, bta, mea, var, out);
}

// Round 6
// 126.528 us; speedup vs baseline: 1.0686x; 1.0686x over previous
//
#include <hip/hip_runtime.h>
#include <hip/hip_bf16.h>
#include <hip/hip_fp16.h>
#include <math.h>

#define BB 4
#define CC 192
#define HH 56
#define WW 56
#define HWW 3136

typedef __attribute__((ext_vector_type(8))) short short8;
typedef __attribute__((ext_vector_type(4))) float f32x4;

__device__ __forceinline__ unsigned short f2b(float f) {
    __hip_bfloat16 h = __float2bfloat16(f);
    return __builtin_bit_cast(unsigned short, h);
}
__device__ __forceinline__ float b2f(unsigned short u) {
    unsigned int x = ((unsigned int)u) << 16;
    return __builtin_bit_cast(float, x);
}
__device__ __forceinline__ unsigned short f2h(float f) {
    __half h = __float2half_rn(f);
    return __builtin_bit_cast(unsigned short, h);
}
__device__ __forceinline__ float2 h2f2(unsigned int u) {
    return __half22float2(__builtin_bit_cast(__half2, u));
}

// ---------------------------------------------------------------------------
// Kernel 1: blocks [0,2352): transpose x (B,C,H,W) -> split-bf16 xth/xtl (B,HW,C)
//           blocks [2352,2640): W' = [C1;C2] -> split bf16 (N=384, K=192)
// ---------------------------------------------------------------------------
__global__ __launch_bounds__(256) void k_pre(const float* __restrict__ x,
                                             const float* __restrict__ cw,
                                             unsigned short* __restrict__ xth,
                                             unsigned short* __restrict__ xtl,
                                             unsigned short* __restrict__ cwh,
                                             unsigned short* __restrict__ cwl) {
    int tid = threadIdx.x, bid = blockIdx.x;
    if (bid < 2352) {
        __shared__ float tile[32][33];
        int b = bid / 588, rem = bid % 588;
        int by = rem / 98, bx = rem % 98;
        int tx = tid & 31, ty = tid >> 5;
        int p0 = bx * 32, c0 = by * 32;
#pragma unroll
        for (int i = 0; i < 4; i++) {
            int c = c0 + ty + 8 * i;
            tile[ty + 8 * i][tx] = x[(b * CC + c) * HWW + p0 + tx];
        }
        __syncthreads();
#pragma unroll
        for (int i = 0; i < 4; i++) {
            int p = p0 + ty + 8 * i;
            float v = tile[tx][ty + 8 * i];
            unsigned short hi = f2b(v);
            size_t o = (size_t)(b * HWW + p) * CC + c0 + tx;
            xth[o] = hi;
            xtl[o] = f2b(v - b2f(hi));
        }
    } else {
        int i = (bid - 2352) * 256 + tid;     // 288*256 = 73728 = 384*192 exact
        if (i < 384 * 192) {
            int n = i / 192, k = i % 192;
            float v = (n < 192) ? cw[n * 384 + k] : cw[(n - 192) * 384 + 192 + k];
            unsigned short hi = f2b(v);
            cwh[i] = hi;
            cwl[i] = f2b(v - b2f(hi));
        }
    }
}

// ---------------------------------------------------------------------------
// Kernel 2 (fused independent work, reads xth/xtl/cwh/cwl only):
//   blocks [0,1792):    scores (pair symmetry) -> sp [half][b][pix][32]
//   blocks [1792,2968): GEMM [u|z] = W'·x^T, M=12544, N=384, K=192, split-bf16.
// ---------------------------------------------------------------------------
__global__ __launch_bounds__(256) void k_mid(const unsigned short* __restrict__ xth,
                                             const unsigned short* __restrict__ xtl,
                                             const unsigned short* __restrict__ cwh,
                                             const unsigned short* __restrict__ cwl,
                                             float* __restrict__ sp,
                                             float* __restrict__ u,
                                             float* __restrict__ z) {
    __shared__ __align__(16) char smem[36864];
    int tid = threadIdx.x, bid = blockIdx.x;

    if (bid < 1792) {                 // ---------------- scores ----------------
        float* Xs = (float*)smem;     // 28 rows x 96ch (+4 pad), f32 reconstructed
        const float K2 = 0.38490017945975050f;  // 2/sqrt(27)
        bool isH = bid < 896;
        int lid = isH ? bid : bid - 896;
        int half = lid & 1;
        int rp = (lid >> 1) & 1;
        int cb2 = lid >> 2;
        int b = cb2 / 56, l0 = cb2 % 56;
        int r0 = rp * 2;

        const unsigned short* srch = xth + (size_t)(b * HWW) * CC + half * 96;
        const unsigned short* srcl = xtl + (size_t)(b * HWW) * CC + half * 96;
        for (int idx = tid; idx < 28 * 12; idx += 256) {
            int t2 = idx / 12, cq = idx % 12;
            int pi = (r0 + t2 / 14) + 4 * (t2 % 14);
            int pix = isH ? (pi * WW + l0) : (l0 * WW + pi);
            short8 h8 = *(const short8*)(srch + (size_t)pix * CC + cq * 8);
            short8 l8 = *(const short8*)(srcl + (size_t)pix * CC + cq * 8);
            float o[8];
#pragma unroll
            for (int e = 0; e < 8; e++)
                o[e] = b2f((unsigned short)h8[e]) + b2f((unsigned short)l8[e]);
            *(float4*)&Xs[t2 * 100 + cq * 8] = *(float4*)&o[0];
            *(float4*)&Xs[t2 * 100 + cq * 8 + 4] = *(float4*)&o[4];
        }
        __syncthreads();

        int perCls = isH ? 105 : 91;
        if (tid < 2 * perCls) {
            int cls = tid / perCls, p = tid % perCls;
            int a, bb;
            if (isH) {
                a = (int)((sqrtf((float)(8 * p + 1)) - 1.0f) * 0.5f);
                bb = p - (a * (a + 1)) / 2;
            } else {
                int ap = (int)((sqrtf((float)(8 * p + 1)) - 1.0f) * 0.5f);
                bb = p - (ap * (ap + 1)) / 2;
                a = ap + 1;
            }
            const float* pA = &Xs[(cls * 14 + a) * 100];
            const float* pB = &Xs[(cls * 14 + bb) * 100];
            float s0 = 0.f, s1 = 0.f, s2 = 0.f, s3 = 0.f;
#pragma unroll
            for (int q = 0; q < 24; q++) {
                float4 av = *(const float4*)(pA + q * 4);
                float4 bv = *(const float4*)(pB + q * 4);
                s0 += __builtin_amdgcn_rcpf(__expf(av.x * bv.x * K2) + 1.0f);
                s1 += __builtin_amdgcn_rcpf(__expf(av.y * bv.y * K2) + 1.0f);
                s2 += __builtin_amdgcn_rcpf(__expf(av.z * bv.z * K2) + 1.0f);
                s3 += __builtin_amdgcn_rcpf(__expf(av.w * bv.w * K2) + 1.0f);
            }
            float s = 96.0f - 2.0f * (s0 + s1 + s2 + s3);   // sum_c tanh
            int r = r0 + cls;
            size_t base = (size_t)(half * BB + b) * HWW;
            if (isH) {
                int i1 = a - bb;
                int h1 = r + 4 * a, h2 = r + 4 * bb;
                sp[(base + h1 * WW + l0) * 32 + i1] = s;
                if (a != bb) sp[(base + h2 * WW + l0) * 32 + (14 - i1)] = s;
            } else {
                int d = a - bb;                        // 1..13
                int w1 = r + 4 * a, w2 = r + 4 * bb;
                sp[(base + l0 * WW + w1) * 32 + 14 + (d - 1)] = s;
                sp[(base + l0 * WW + w2) * 32 + 14 + (13 - d)] = s;
            }
        }
        return;
    }

    // ---------------- GEMM [u|z], split-bf16, tile 64x64, K=192 ----------------
    {
        unsigned short* Ah = (unsigned short*)smem;
        unsigned short* Al = Ah + 64 * 72;
        unsigned short* Bh = Ah + 2 * 64 * 72;
        unsigned short* Bl = Ah + 3 * 64 * 72;
        float* Ds = (float*)smem;
        int vb = bid - 1792;                  // 0..1175
        int bm = (vb % 196) * 64, bn = (vb / 196) * 64;
        int lane = tid & 63, wv = tid >> 6;

        f32x4 acc[4] = {{0,0,0,0},{0,0,0,0},{0,0,0,0},{0,0,0,0}};

        for (int kc = 0; kc < 3; kc++) {
#pragma unroll
            for (int r2 = 0; r2 < 2; r2++) {
                int idx = tid + r2 * 256;
                int m = idx >> 3, kq = idx & 7;
                size_t ao = (size_t)(bm + m) * CC + kc * 64 + kq * 8;
                *(short8*)&Ah[m * 72 + kq * 8] = *(const short8*)(xth + ao);
                *(short8*)&Al[m * 72 + kq * 8] = *(const short8*)(xtl + ao);
                size_t bo = (size_t)(bn + m) * 192 + kc * 64 + kq * 8;
                *(short8*)&Bh[m * 72 + kq * 8] = *(const short8*)(cwh + bo);
                *(short8*)&Bl[m * 72 + kq * 8] = *(const short8*)(cwl + bo);
            }
            __syncthreads();
            int n0 = wv * 16;
            int k8 = lane >> 4;
            int col = lane & 15;
#pragma unroll
            for (int ks = 0; ks < 64; ks += 32) {
                int koff = ks + k8 * 8;
                short8 bfh = *(const short8*)&Bh[(n0 + col) * 72 + koff];
                short8 bfl = *(const short8*)&Bl[(n0 + col) * 72 + koff];
#pragma unroll
                for (int fm = 0; fm < 4; fm++) {
                    short8 afh = *(const short8*)&Ah[(fm * 16 + col) * 72 + koff];
                    short8 afl = *(const short8*)&Al[(fm * 16 + col) * 72 + koff];
                    acc[fm] = __builtin_amdgcn_mfma_f32_16x16x32_bf16(afh, bfh, acc[fm], 0, 0, 0);
                    acc[fm] = __builtin_amdgcn_mfma_f32_16x16x32_bf16(afl, bfh, acc[fm], 0, 0, 0);
                    acc[fm] = __builtin_amdgcn_mfma_f32_16x16x32_bf16(afh, bfl, acc[fm], 0, 0, 0);
                }
            }
            __syncthreads();
        }
        // LDS transpose: Ds[m][n], stride 68
        {
            int col = lane & 15, rowq = lane >> 4;
#pragma unroll
            for (int fm = 0; fm < 4; fm++)
#pragma unroll
                for (int rg = 0; rg < 4; rg++)
                    Ds[(fm * 16 + rowq * 4 + rg) * 68 + wv * 16 + col] = acc[fm][rg];
        }
        __syncthreads();
        // Store pixel-major: u (n<192) or z (n>=192)
        {
            int c4 = tid & 15, m0 = tid >> 4;
            int cg = bn + c4 * 4;
            float* dst = (cg < 192) ? u : z;
            int cc = (cg < 192) ? cg : cg - 192;
#pragma unroll
            for (int p = 0; p < 4; p++) {
                int m = m0 + p * 16;
                float4 v = *(float4*)&Ds[m * 68 + c4 * 4];
                *(float4*)&dst[(size_t)(bm + m) * CC + cc] = v;
            }
        }
    }
}

// ---------------------------------------------------------------------------
// Kernel 3: per-pixel softmax over 27 scores -> f16 weights wn16[pix][32]
// (slots 27..31 = 0). 49 blocks x 256 threads = 12544 pixels exactly.
// Softmax computed ONCE per pixel chip-wide.
// ---------------------------------------------------------------------------
__global__ __launch_bounds__(256) void k_soft(const float* __restrict__ sp,
                                              unsigned short* __restrict__ wn16) {
    int gp = blockIdx.x * 256 + threadIdx.x;           // b*3136 + pix
    const float4* p0 = (const float4*)&sp[(size_t)gp * 32];
    const float4* p1 = (const float4*)&sp[((size_t)(4 * HWW) + gp) * 32];
    float sc[28];
#pragma unroll
    for (int j = 0; j < 7; j++) {
        float4 a = p0[j], v = p1[j];
        sc[4 * j + 0] = a.x + v.x; sc[4 * j + 1] = a.y + v.y;
        sc[4 * j + 2] = a.z + v.z; sc[4 * j + 3] = a.w + v.w;
    }
    float mx = -1e30f;
#pragma unroll
    for (int s = 0; s < 27; s++) mx = fmaxf(mx, sc[s]);
    float sum = 0.f;
#pragma unroll
    for (int s = 0; s < 27; s++) { sc[s] = __expf(sc[s] - mx); sum += sc[s]; }
    float inv = __builtin_amdgcn_rcpf(sum);

    unsigned short hw[32];
#pragma unroll
    for (int s = 0; s < 27; s++) hw[s] = f2h(sc[s] * inv);
#pragma unroll
    for (int s = 27; s < 32; s++) hw[s] = 0;
    unsigned short* dst = wn16 + (size_t)gp * 32;
#pragma unroll
    for (int q = 0; q < 4; q++)
        *(short8*)(dst + q * 8) = *(short8*)&hw[q * 8];
}

// ---------------------------------------------------------------------------
// Kernel 4: fused H+W accumulation + bias + BN + GELU.
// Block = (b, r-phase, 8-ch chunk, t-half). LDS: z slab (25KB) + this block's
// 392-pixel f16 weight slab (28KB, stride 36 -> conflict-free h2-reads).
// Weights are bulk-copied global->LDS once per block (no redundant softmax).
// Grid 768 = 4b x 4r x 24cc x 2th, 448 threads (tid = w*8+c).
// ---------------------------------------------------------------------------
__global__ __launch_bounds__(448, 1) void k_tail(const float* __restrict__ u,
                                                 const float* __restrict__ z,
                                                 const unsigned short* __restrict__ wn16,
                                                 const float* __restrict__ cb,
                                                 const float* __restrict__ gma,
                                                 const float* __restrict__ bta,
                                                 const float* __restrict__ mea,
                                                 const float* __restrict__ var,
                                                 float* __restrict__ y) {
    __shared__ float Zs[14 * 56 * 8];            // 25088 B, [t][w][c]
    __shared__ unsigned short W16[7 * 56 * 36];  // 28224 B, [tq][w][36] (pad)
    int tid = threadIdx.x, bid = blockIdx.x;
    int th = bid & 1;
    int t1 = bid >> 1;                    // 0..383
    int cc = t1 % 24;
    int t2 = t1 / 24;                     // 0..15
    int r = t2 & 3;
    int b = t2 >> 2;
    int w = tid >> 3, c = tid & 7;
    int cg = cc * 8 + c;
    int hbase = r + 4 * (th * 7);

    // stage z slab: rows r, r+4, ..., r+52 (all 14 t); channels [cc*8, cc*8+8)
#pragma unroll
    for (int it = 0; it < 2; it++) {
        int idx = tid + it * 448;
        if (idx < 784) {
            int t = idx / 56, ww = idx - t * 56;
            const float* s = z + ((size_t)(b * HWW + (r + 4 * t) * WW + ww)) * CC + cc * 8;
            float4 v0 = *(const float4*)s;
            float4 v1 = *(const float4*)(s + 4);
            float* d = &Zs[(t * 56 + ww) * 8];
            *(float4*)d = v0;
            *(float4*)(d + 4) = v1;
        }
    }
    // stage weight slab: this block's 392 pixels x 32 halves (64B each),
    // 16B chunks: i = pix_local*4 + q.  Global is contiguous per row.
    for (int i = tid; i < 392 * 4; i += 448) {
        int pl = i >> 2, q = i & 3;
        int tq = pl / 56, ww = pl - tq * 56;
        int row = hbase + 4 * tq;
        size_t gsrc = ((size_t)(b * HWW + row * WW + ww)) * 32 + q * 8;
        short8 v = *(const short8*)(wn16 + gsrc);
        *(short8*)&W16[(tq * 56 + ww) * 36 + q * 8] = v;
    }
    __syncthreads();

    // this thread's z column, pre-rotated by th*7 so all reg indices are static
    float zc[14];
#pragma unroll
    for (int m = 0; m < 14; m++) {
        int t0 = m + th * 7;
        if (t0 >= 14) t0 -= 14;
        zc[m] = Zs[(t0 * 56 + w) * 8 + c];
    }

    float bias = cb[cg];
    float ginv = gma[cg] * rsqrtf(var[cg] + 1e-5f);
    float bt = bta[cg];
    float me = mea[cg];

    float acc0[7];
#pragma unroll
    for (int tt = 0; tt < 7; tt++) {
        int pix = (hbase + 4 * tt) * WW + w;
        acc0[tt] = u[((size_t)(b * HWW + pix)) * CC + cg];
    }

#pragma unroll
    for (int tt = 0; tt < 7; tt++) {
        int t = th * 7 + tt;
        int pix = (hbase + 4 * tt) * WW + w;
        int pb = (tt * 56 + w) * 36;
        float a = acc0[tt];

        // H-part: halves 0..13 = wt[i], zc rotated so indices are static
#pragma unroll
        for (int p = 0; p < 7; p++) {
            float2 f2 = h2f2(*(const unsigned int*)&W16[pb + 2 * p]);
            a += f2.x * zc[(tt - 2 * p + 28) % 14];
            a += f2.y * zc[(tt - 2 * p - 1 + 28) % 14];
        }
        // W-part: halves 14..26 = wt[13+j] (j=1..13); half 27 = 0 pad
#pragma unroll
        for (int p = 7; p < 14; p++) {
            float2 f2 = h2f2(*(const unsigned int*)&W16[pb + 2 * p]);
            int j0 = 2 * p - 13, j1 = 2 * p - 12;
            int wj0 = w - 4 * j0; if (wj0 < 0) wj0 += 56;
            int wj1 = w - 4 * j1; if (wj1 < 0) wj1 += 56;
            a += f2.x * Zs[(t * 56 + wj0) * 8 + c];
            a += f2.y * Zs[(t * 56 + wj1) * 8 + c];
        }

        float v = (a + bias - me) * ginv + bt;
        v = 0.5f * v * (1.0f + erff(v * 0.70710678118654752f));
        y[((size_t)(b * CC + cg)) * HWW + pix] = v;
    }
}

// ---------------------------------------------------------------------------
extern "C" void kernel_launch(void* const* d_in, const int* in_sizes, int n_in,
                              void* d_out, int out_size, void* d_ws, size_t ws_size,
                              hipStream_t stream) {
    const float* x   = (const float*)d_in[0];
    const float* cw  = (const float*)d_in[1];
    const float* cb  = (const float*)d_in[2];
    const float* gma = (const float*)d_in[3];
    const float* bta = (const float*)d_in[4];
    const float* mea = (const float*)d_in[5];
    const float* var = (const float*)d_in[6];
    float* out = (float*)d_out;

    float* ws = (float*)d_ws;
    float*          sp   = ws;                                  //   802,816 f
    float*          u    = ws + 802816;                         // 2,408,448 f
    float*          z    = ws + 3211264;                        // 2,408,448 f
    unsigned short* xth  = (unsigned short*)(ws + 5619712);     // 2,408,448 us
    unsigned short* xtl  = (unsigned short*)(ws + 6823936);     // 2,408,448 us
    unsigned short* cwh  = (unsigned short*)(ws + 8028160);     //  73,728 us -> ends 8,065,024
    unsigned short* cwl  = (unsigned short*)(ws + 8065024);     //  73,728 us -> ends 8,101,888
    unsigned short* wn16 = (unsigned short*)(ws + 8101888);     // 401,408 us

    k_pre<<<2640, 256, 0, stream>>>(x, cw, xth, xtl, cwh, cwl);
    k_mid<<<2968, 256, 0, stream>>>(xth, xtl, cwh, cwl, sp, u, z);
    k_soft<<<49, 256, 0, stream>>>(sp, wn16);
    k_tail<<<768, 448, 0, stream>>>(u, z, wn16, cb, gma, bta, mea, var, out);
}